// Round 1
// baseline (113.645 us; speedup 1.0000x reference)
//
#include <hip/hip_runtime.h>

typedef float f2 __attribute__((ext_vector_type(2)));
typedef float f4 __attribute__((ext_vector_type(4)));
typedef _Float16 h4 __attribute__((ext_vector_type(4)));

constexpr int Hh = 224, Ww = 224, Bb = 8, Kc = 4, RAD = 5;

// 128 threads = 32x4; each thread computes 4 vertically-adjacent pixels -> 32x16 tile
constexpr int TX = 32;
constexpr int TILEH = 16;
constexpr int PPT = 4;                // pixels per thread (vertical)
constexpr int NTHR = TX * (TILEH / PPT);  // 128
constexpr int SW = TX + 2 * RAD;      // 42
constexpr int SH = TILEH + 2 * RAD;   // 26
constexpr int SSTR = SW + 1;          // 43 (odd -> conflict-free; col 42 = pad column)
constexpr int GXD = Ww / TX;          // 7
constexpr int GYD = Hh / TILEH;       // 14
constexpr int PB = GXD * GYD;         // 98 blocks per batch image

constexpr float LOG2E = 1.44269504f;
constexpr float KI = -0.01f * LOG2E;        // intensity coeff (pre-scaled for exp2)
constexpr float DSC = -0.0625f * LOG2E;     // dist coeff     (pre-scaled for exp2)
// column dist term, pre-multiplied by DSC.
// Index 11 is dx=+6 (outside the 11-wide window): -1e5 forces exp2 -> 0 exactly,
// fixing the spurious-tap bug (old D2[11]=0 added a full-weight 122nd tap).
constexpr float DC[12] = {25.f * DSC, 16.f * DSC, 9.f * DSC, 4.f * DSC, 1.f * DSC, 0.f,
                          1.f * DSC, 4.f * DSC, 9.f * DSC, 16.f * DSC, 25.f * DSC, -1e5f};

static __device__ inline f4 splat4(float x) { return (f4){x, x, x, x}; }

__global__ __launch_bounds__(NTHR, 4) void ncut_main(const float* __restrict__ images,
                                                     const float* __restrict__ labels,
                                                     float* __restrict__ acc) {
    __shared__ float simg[SH * SSTR];
    __shared__ h4    slab[SH * SSTR];
    __shared__ float red[2][8];

    const int b   = blockIdx.z;
    const int x0  = blockIdx.x * TX;
    const int y0  = blockIdx.y * TILEH;
    const int tid = threadIdx.x;

    const float* imgb = images + (size_t)b * (Hh * Ww);
    const float* labb = labels + (size_t)b * (Kc * Hh * Ww);

    // Stage tile + halo. OOB: img = 1e19 -> exp2 arg ~ -1.4e36 -> weight exactly 0; labels = 0.
    for (int idx = tid; idx < SH * SSTR; idx += NTHR) {
        const int lx = idx % SSTR, ly = idx / SSTR;
        const int gx = x0 - RAD + lx, gy = y0 - RAD + ly;
        float iv = 1e19f;
        h4 lv = (h4){(_Float16)0.f, (_Float16)0.f, (_Float16)0.f, (_Float16)0.f};
        if (lx < SW && gx >= 0 && gx < Ww && gy >= 0 && gy < Hh) {
            const int g = gy * Ww + gx;
            iv = imgb[g] * 255.0f;
            lv = (h4){(_Float16)labb[g], (_Float16)labb[Hh * Ww + g],
                      (_Float16)labb[2 * Hh * Ww + g], (_Float16)labb[3 * Hh * Ww + g]};
        }
        simg[idx] = iv;
        slab[idx] = lv;
    }
    __syncthreads();

    const int tx = tid & (TX - 1);
    const int ty = tid >> 5;          // 0..3
    const int r0 = PPT * ty;          // top LDS row of this thread's 14-row window

    // hoisted per-center constants: a = KI*(v-c)^2 + Dc + Dr
    //                                 = v*(KI*v + q1) + Dc + (KI*c^2 + Dr)
    float q1[PPT], kc2[PPT];
#pragma unroll
    for (int p = 0; p < PPT; ++p) {
        const float c = simg[(r0 + p + RAD) * SSTR + tx + RAD];
        q1[p]  = (-2.0f * KI) * c;
        kc2[p] = (KI * c) * c;
    }

    f4 num[PPT];
    f2 den[PPT];
#pragma unroll
    for (int p = 0; p < PPT; ++p) {
        num[p] = (f4){0.f, 0.f, 0.f, 0.f};
        den[p] = (f2){0.f, 0.f};
    }

    const f2 kis = (f2){KI, KI};

    // 14 shared rows serve 4 centers: center p active for dr in [p, p+10]
#pragma unroll 1
    for (int dr = 0; dr < 11 + PPT - 1; ++dr) {
        const int rowoff = (r0 + dr) * SSTR + tx;

        float beta[PPT];
#pragma unroll
        for (int p = 0; p < PPT; ++p) {
            const float fdy = (float)(dr - p - RAD);
            beta[p] = __builtin_fmaf(DSC * fdy, fdy, kc2[p]);
        }

        // two half-rows of 3 f2-pairs each, register-blocked so all 4 centers share the loads
#pragma unroll
        for (int h = 0; h < 2; ++h) {
            const int bi = 3 * h;
            f2 v[3];
            f4 a0[3], a1[3];
#pragma unroll
            for (int i = 0; i < 3; ++i) {
                const int off = rowoff + 2 * (bi + i);
                v[i]  = (f2){simg[off], simg[off + 1]};
                a0[i] = __builtin_convertvector(slab[off], f4);
                a1[i] = __builtin_convertvector(slab[off + 1], f4);
            }
#pragma unroll
            for (int p = 0; p < PPT; ++p) {
                if (dr >= p && dr <= p + 10) {   // wave-uniform scalar branch
#pragma unroll
                    for (int i = 0; i < 3; ++i) {
                        const int col = bi + i;
                        const f2 dc = (f2){DC[2 * col], DC[2 * col + 1]};
                        const f2 t1 = __builtin_elementwise_fma(v[i], kis, (f2){q1[p], q1[p]});
                        const f2 t2 = __builtin_elementwise_fma(v[i], t1, dc);
                        const float e0 = __builtin_amdgcn_exp2f(t2.x + beta[p]);
                        const float e1 = __builtin_amdgcn_exp2f(t2.y + beta[p]);
                        den[p] += (f2){e0, e1};
                        num[p] = __builtin_elementwise_fma(splat4(e0), a0[i], num[p]);
                        num[p] = __builtin_elementwise_fma(splat4(e1), a1[i], num[p]);
                    }
                }
            }
        }
    }

    // per-class sums of p_f * num and p_f * den over this thread's 4 pixels
    f4 numv = splat4(0.f), denv = splat4(0.f);
#pragma unroll
    for (int p = 0; p < PPT; ++p) {
        const f4 pc = __builtin_convertvector(slab[(r0 + p + RAD) * SSTR + tx + RAD], f4);
        const float dn = den[p].x + den[p].y;
        numv = __builtin_elementwise_fma(pc, num[p], numv);
        denv = __builtin_elementwise_fma(pc, splat4(dn), denv);
    }

    float vals[8] = {numv.x, numv.y, numv.z, numv.w, denv.x, denv.y, denv.z, denv.w};

#pragma unroll
    for (int i = 0; i < 8; ++i) {
        float vv = vals[i];
#pragma unroll
        for (int off = 32; off > 0; off >>= 1) vv += __shfl_down(vv, off, 64);
        vals[i] = vv;
    }

    const int wave = tid >> 6, lane = tid & 63;
    if (lane == 0) {
#pragma unroll
        for (int i = 0; i < 8; ++i) red[wave][i] = vals[i];
    }
    __syncthreads();

    if (tid < 8) {
        const int gid = blockIdx.x + GXD * blockIdx.y + GXD * GYD * blockIdx.z;
        acc[gid * 8 + tid] = red[0][tid] + red[1][tid];
    }
}

__global__ void ncut_final(const float* __restrict__ acc, float* __restrict__ out) {
    __shared__ float red[4][64];
    const int t = threadIdx.x;           // 0..255
    const int combo = t & 63;
    const int chunk = t >> 6;            // 0..3
    const int k = combo & 3, b = (combo >> 2) & 7;
    const int part = combo >> 5;         // 0 = num, 1 = den
    float s = 0.f;
    for (int j = chunk; j < PB; j += 4)
        s += acc[(b * PB + j) * 8 + k + 4 * part];
    red[chunk][combo] = s;
    __syncthreads();
    if (t < 64) {
        float v = red[0][t] + red[1][t] + red[2][t] + red[3][t];
        const float den = __shfl(v, (t + 32) & 63, 64);
        float r = (t < 32) ? fabsf(v / den) : 0.f;
#pragma unroll
        for (int off = 32; off > 0; off >>= 1) r += __shfl_down(r, off, 64);
        if (t == 0) out[0] = (float)Kc - r * (1.0f / (float)Bb);
    }
}

extern "C" void kernel_launch(void* const* d_in, const int* in_sizes, int n_in,
                              void* d_out, int out_size, void* d_ws, size_t ws_size,
                              hipStream_t stream) {
    const float* images = (const float*)d_in[0];
    const float* labels = (const float*)d_in[1];
    float* out = (float*)d_out;
    float* acc = (float*)d_ws;  // PB*Bb blocks * 8 partials, fully overwritten each launch

    dim3 grid(GXD, GYD, Bb);    // 7 x 14 x 8
    ncut_main<<<grid, NTHR, 0, stream>>>(images, labels, acc);
    ncut_final<<<1, 256, 0, stream>>>(acc, out);
}

// Round 2
// 102.854 us; speedup vs baseline: 1.1049x; 1.1049x over previous
//
#include <hip/hip_runtime.h>

typedef float f2 __attribute__((ext_vector_type(2)));
typedef float f4 __attribute__((ext_vector_type(4)));
typedef _Float16 h4 __attribute__((ext_vector_type(4)));

constexpr int Hh = 224, Ww = 224, Bb = 8, Kc = 4, RAD = 5;

// 128 threads = 32x4; each thread computes 2 vertically-adjacent pixels -> 32x8 tile
constexpr int TX = 32;
constexpr int TILEH = 8;
constexpr int PPT = 2;                    // pixels per thread (vertical)
constexpr int NTHR = TX * (TILEH / PPT);  // 128
constexpr int SW = TX + 2 * RAD;          // 42
constexpr int SH = TILEH + 2 * RAD;       // 18
constexpr int SSTR = SW + 1;              // 43 (odd -> conflict-free; col 42 = pad column)
constexpr int GXD = Ww / TX;              // 7
constexpr int GYD = Hh / TILEH;           // 28
constexpr int PB = GXD * GYD;             // 196 blocks per batch image

constexpr float LOG2E = 1.44269504f;
constexpr float KI = -0.01f * LOG2E;        // intensity coeff (pre-scaled for exp2)
constexpr float DSC = -0.0625f * LOG2E;     // dist coeff     (pre-scaled for exp2)
// column dist term, pre-multiplied by DSC.
// Index 11 is dx=+6 (outside the 11-wide window): -1e5 forces exp2 -> 0 exactly.
constexpr float DC[12] = {25.f * DSC, 16.f * DSC, 9.f * DSC, 4.f * DSC, 1.f * DSC, 0.f,
                          1.f * DSC, 4.f * DSC, 9.f * DSC, 16.f * DSC, 25.f * DSC, -1e5f};

static __device__ inline f4 splat4(float x) { return (f4){x, x, x, x}; }

__global__ __launch_bounds__(NTHR, 4) void ncut_main(const float* __restrict__ images,
                                                     const float* __restrict__ labels,
                                                     float* __restrict__ acc) {
    __shared__ float simg[SH * SSTR];
    __shared__ h4    slab[SH * SSTR];
    __shared__ float red[2][8];

    const int b   = blockIdx.z;
    const int x0  = blockIdx.x * TX;
    const int y0  = blockIdx.y * TILEH;
    const int tid = threadIdx.x;

    const float* imgb = images + (size_t)b * (Hh * Ww);
    const float* labb = labels + (size_t)b * (Kc * Hh * Ww);

    // Stage tile + halo. OOB: img = 1e19 -> exp2 arg ~ -1.4e36 -> weight exactly 0; labels = 0.
    for (int idx = tid; idx < SH * SSTR; idx += NTHR) {
        const int lx = idx % SSTR, ly = idx / SSTR;
        const int gx = x0 - RAD + lx, gy = y0 - RAD + ly;
        float iv = 1e19f;
        h4 lv = (h4){(_Float16)0.f, (_Float16)0.f, (_Float16)0.f, (_Float16)0.f};
        if (lx < SW && gx >= 0 && gx < Ww && gy >= 0 && gy < Hh) {
            const int g = gy * Ww + gx;
            iv = imgb[g] * 255.0f;
            lv = (h4){(_Float16)labb[g], (_Float16)labb[Hh * Ww + g],
                      (_Float16)labb[2 * Hh * Ww + g], (_Float16)labb[3 * Hh * Ww + g]};
        }
        simg[idx] = iv;
        slab[idx] = lv;
    }
    __syncthreads();

    const int tx = tid & (TX - 1);
    const int ty = tid >> 5;          // 0..3
    const int r0 = PPT * ty;          // top LDS row of this thread's 12-row window

    const float c0 = simg[(r0 + RAD) * SSTR + tx + RAD];
    const float c1 = simg[(r0 + RAD + 1) * SSTR + tx + RAD];

    // hoisted per-center constants: arg = v*(KI*v + q1) + DC[col] + (KI*c^2 + DSC*dy^2)
    const float q10  = (-2.0f * KI) * c0;
    const float q11  = (-2.0f * KI) * c1;
    const float kc20 = (KI * c0) * c0;
    const float kc21 = (KI * c1) * c1;

    f4 num0 = splat4(0.f), num1 = splat4(0.f);
    f2 den0 = (f2){0.f, 0.f}, den1 = (f2){0.f, 0.f};

    const f2 kis = (f2){KI, KI};

    // 12 shared rows serve 2 centers: c0 active for dr in [0,10], c1 for dr in [1,11].
    // Fully unrolled: all guards are compile-time; compiler pipelines row r+1 loads
    // under row r math.
#pragma unroll
    for (int dr = 0; dr < 12; ++dr) {
        const int rowoff = (r0 + dr) * SSTR + tx;

        const float dy0 = (float)((dr - 5) * (dr - 5));   // compile-time constants
        const float dy1 = (float)((dr - 6) * (dr - 6));
        const float beta0 = __builtin_fmaf(DSC, dy0, kc20);
        const float beta1 = __builtin_fmaf(DSC, dy1, kc21);

#pragma unroll
        for (int i = 0; i < 6; ++i) {
            const int off = rowoff + 2 * i;
            const f2 v  = (f2){simg[off], simg[off + 1]};
            const f4 p0 = __builtin_convertvector(slab[off], f4);
            const f4 p1 = __builtin_convertvector(slab[off + 1], f4);
            const f2 dc = (f2){DC[2 * i], DC[2 * i + 1]};
            if (dr < 11) {
                const f2 t1 = __builtin_elementwise_fma(v, kis, (f2){q10, q10});
                const f2 t2 = __builtin_elementwise_fma(v, t1, dc + (f2){beta0, beta0});
                const float e0 = __builtin_amdgcn_exp2f(t2.x);
                const float e1 = __builtin_amdgcn_exp2f(t2.y);
                den0 += (f2){e0, e1};
                num0 = __builtin_elementwise_fma(splat4(e0), p0, num0);
                num0 = __builtin_elementwise_fma(splat4(e1), p1, num0);
            }
            if (dr >= 1) {
                const f2 t1 = __builtin_elementwise_fma(v, kis, (f2){q11, q11});
                const f2 t2 = __builtin_elementwise_fma(v, t1, dc + (f2){beta1, beta1});
                const float e0 = __builtin_amdgcn_exp2f(t2.x);
                const float e1 = __builtin_amdgcn_exp2f(t2.y);
                den1 += (f2){e0, e1};
                num1 = __builtin_elementwise_fma(splat4(e0), p0, num1);
                num1 = __builtin_elementwise_fma(splat4(e1), p1, num1);
            }
        }
    }

    // per-class sums of p_f * num and p_f * den over this thread's 2 pixels
    const f4 pc0 = __builtin_convertvector(slab[(r0 + RAD) * SSTR + tx + RAD], f4);
    const f4 pc1 = __builtin_convertvector(slab[(r0 + RAD + 1) * SSTR + tx + RAD], f4);
    const float dn0 = den0.x + den0.y;
    const float dn1 = den1.x + den1.y;

    const f4 numv = pc0 * num0 + pc1 * num1;
    const f4 denv = pc0 * dn0 + pc1 * dn1;

    float vals[8] = {numv.x, numv.y, numv.z, numv.w, denv.x, denv.y, denv.z, denv.w};

#pragma unroll
    for (int i = 0; i < 8; ++i) {
        float vv = vals[i];
#pragma unroll
        for (int off = 32; off > 0; off >>= 1) vv += __shfl_down(vv, off, 64);
        vals[i] = vv;
    }

    const int wave = tid >> 6, lane = tid & 63;
    if (lane == 0) {
#pragma unroll
        for (int i = 0; i < 8; ++i) red[wave][i] = vals[i];
    }
    __syncthreads();

    if (tid < 8) {
        const int gid = blockIdx.x + GXD * blockIdx.y + GXD * GYD * blockIdx.z;
        acc[gid * 8 + tid] = red[0][tid] + red[1][tid];
    }
}

__global__ void ncut_final(const float* __restrict__ acc, float* __restrict__ out) {
    __shared__ float red[4][64];
    const int t = threadIdx.x;           // 0..255
    const int combo = t & 63;
    const int chunk = t >> 6;            // 0..3
    const int k = combo & 3, b = (combo >> 2) & 7;
    const int part = combo >> 5;         // 0 = num, 1 = den
    float s = 0.f;
    for (int j = chunk; j < PB; j += 4)
        s += acc[(b * PB + j) * 8 + k + 4 * part];
    red[chunk][combo] = s;
    __syncthreads();
    if (t < 64) {
        float v = red[0][t] + red[1][t] + red[2][t] + red[3][t];
        const float den = __shfl(v, (t + 32) & 63, 64);
        float r = (t < 32) ? fabsf(v / den) : 0.f;
#pragma unroll
        for (int off = 32; off > 0; off >>= 1) r += __shfl_down(r, off, 64);
        if (t == 0) out[0] = (float)Kc - r * (1.0f / (float)Bb);
    }
}

extern "C" void kernel_launch(void* const* d_in, const int* in_sizes, int n_in,
                              void* d_out, int out_size, void* d_ws, size_t ws_size,
                              hipStream_t stream) {
    const float* images = (const float*)d_in[0];
    const float* labels = (const float*)d_in[1];
    float* out = (float*)d_out;
    float* acc = (float*)d_ws;  // PB*Bb blocks * 8 partials, fully overwritten each launch

    dim3 grid(GXD, GYD, Bb);    // 7 x 28 x 8
    ncut_main<<<grid, NTHR, 0, stream>>>(images, labels, acc);
    ncut_final<<<1, 256, 0, stream>>>(acc, out);
}

// Round 3
// 88.225 us; speedup vs baseline: 1.2881x; 1.1658x over previous
//
#include <hip/hip_runtime.h>
#include <hip/hip_bf16.h>

typedef float f2 __attribute__((ext_vector_type(2)));
typedef float f4 __attribute__((ext_vector_type(4)));

constexpr int Hh = 224, Ww = 224, Bb = 8, Kc = 4, RAD = 5;

// 256 threads = 32x8; each thread computes 2 vertically-adjacent pixels -> 32x16 tile
constexpr int TX = 32;
constexpr int TILEH = 16;
constexpr int SW = TX + 2 * RAD;      // 42
constexpr int SH = TILEH + 2 * RAD;   // 26
constexpr int SSTR = SW + 1;          // 43 (odd -> conflict-free; col 42 = pad column)
constexpr int GXD = Ww / TX;          // 7
constexpr int GYD = Hh / TILEH;       // 14
constexpr int PB = GXD * GYD;         // 98 blocks per batch image

constexpr float LOG2E = 1.44269504f;
constexpr float KI = -0.01f * LOG2E;         // intensity coeff (pre-scaled for exp2)
constexpr float DSC = -0.0625f * LOG2E;      // dist coeff     (pre-scaled for exp2)
// d^2 per kernel offset; index 11 is dx=+6 (outside the 11-wide window).
// D2[11]=1e5 -> compile-time base ~ -9000 -> exp2 underflows to exactly 0,
// killing the spurious 122nd tap that D2[11]=0 used to admit for tx<31.
constexpr float D2[12] = {25.f,16.f,9.f,4.f,1.f,0.f,1.f,4.f,9.f,16.f,25.f,1e5f};

static __device__ inline f4 splat4(float x) { return (f4){x, x, x, x}; }

__global__ __launch_bounds__(256, 3) void ncut_main(const float* __restrict__ images,
                                                    const float* __restrict__ labels,
                                                    float* __restrict__ acc) {
    __shared__ float simg[SH * SSTR];
    __shared__ f4    slab[SH * SSTR];
    __shared__ float red[4][8];

    const int b   = blockIdx.z;
    const int x0  = blockIdx.x * TX;
    const int y0  = blockIdx.y * TILEH;
    const int tid = threadIdx.x;

    const float* imgb = images + (size_t)b * (Hh * Ww);
    const float* labb = labels + (size_t)b * (Kc * Hh * Ww);

    // Stage tile + halo (incl. the stride-pad column as OOB).
    // OOB: img = 1e19 -> single-exp weight underflows to exactly 0; labels = 0.
    for (int idx = tid; idx < SH * SSTR; idx += 256) {
        const int lx = idx % SSTR, ly = idx / SSTR;
        const int gx = x0 - RAD + lx, gy = y0 - RAD + ly;
        float iv = 1e19f;
        f4 lv = (f4){0.f, 0.f, 0.f, 0.f};
        if (lx < SW && gx >= 0 && gx < Ww && gy >= 0 && gy < Hh) {
            const int g = gy * Ww + gx;
            iv = imgb[g] * 255.0f;
            lv = (f4){labb[g], labb[Hh * Ww + g], labb[2 * Hh * Ww + g], labb[3 * Hh * Ww + g]};
        }
        simg[idx] = iv;
        slab[idx] = lv;
    }
    __syncthreads();

    const int tx = tid & 31;
    const int ty = tid >> 5;      // 0..7
    const int r0 = 2 * ty;        // top LDS row of this thread's 12-row window

    const float c0 = simg[(r0 + RAD) * SSTR + tx + RAD];
    const float c1 = simg[(r0 + RAD + 1) * SSTR + tx + RAD];

    f4 num0 = splat4(0.f), num1 = splat4(0.f);
    f2 den0 = (f2){0.f, 0.f}, den1 = (f2){0.f, 0.f};

    // 12 rows: row dr serves center0 (dy=dr, dr<11) and center1 (dy=dr-1, dr>=1)
#pragma unroll
    for (int dr = 0; dr < 12; ++dr) {
        const int rowoff = (r0 + dr) * SSTR + tx;
#pragma unroll
        for (int i = 0; i < 6; ++i) {
            const f2 v  = (f2){simg[rowoff + 2 * i], simg[rowoff + 2 * i + 1]};
            const f4 p0 = slab[rowoff + 2 * i];
            const f4 p1 = slab[rowoff + 2 * i + 1];
            if (dr < 11) {
                const f2 base = (f2){(D2[2 * i] + D2[dr]) * DSC,
                                     (D2[2 * i + 1] + D2[dr]) * DSC};
                const f2 d = v - c0;
                const f2 a = __builtin_elementwise_fma(d * KI, d, base);
                const float e0 = __builtin_amdgcn_exp2f(a.x);
                const float e1 = __builtin_amdgcn_exp2f(a.y);
                den0 += (f2){e0, e1};
                num0 = __builtin_elementwise_fma(splat4(e0), p0, num0);
                num0 = __builtin_elementwise_fma(splat4(e1), p1, num0);
            }
            if (dr >= 1) {
                const f2 base = (f2){(D2[2 * i] + D2[dr - 1]) * DSC,
                                     (D2[2 * i + 1] + D2[dr - 1]) * DSC};
                const f2 d = v - c1;
                const f2 a = __builtin_elementwise_fma(d * KI, d, base);
                const float e0 = __builtin_amdgcn_exp2f(a.x);
                const float e1 = __builtin_amdgcn_exp2f(a.y);
                den1 += (f2){e0, e1};
                num1 = __builtin_elementwise_fma(splat4(e0), p0, num1);
                num1 = __builtin_elementwise_fma(splat4(e1), p1, num1);
            }
        }
    }

    const f4 pc0 = slab[(r0 + RAD) * SSTR + tx + RAD];
    const f4 pc1 = slab[(r0 + RAD + 1) * SSTR + tx + RAD];
    const float dn0 = den0.x + den0.y;
    const float dn1 = den1.x + den1.y;

    const f4 numv = pc0 * num0 + pc1 * num1;                 // per-class sum p_f * num
    const f4 denv = pc0 * dn0 + pc1 * dn1;                   // per-class sum p_f * den

    float vals[8] = {numv.x, numv.y, numv.z, numv.w, denv.x, denv.y, denv.z, denv.w};

#pragma unroll
    for (int i = 0; i < 8; ++i) {
        float v = vals[i];
#pragma unroll
        for (int off = 32; off > 0; off >>= 1) v += __shfl_down(v, off, 64);
        vals[i] = v;
    }

    const int wave = tid >> 6, lane = tid & 63;
    if (lane == 0) {
#pragma unroll
        for (int i = 0; i < 8; ++i) red[wave][i] = vals[i];
    }
    __syncthreads();

    if (tid < 8) {
        const int gid = blockIdx.x + GXD * blockIdx.y + GXD * GYD * blockIdx.z;
        acc[gid * 8 + tid] = red[0][tid] + red[1][tid] + red[2][tid] + red[3][tid];
    }
}

__global__ void ncut_final(const float* __restrict__ acc, float* __restrict__ out) {
    __shared__ float red[4][64];
    const int t = threadIdx.x;           // 0..255
    const int combo = t & 63;
    const int chunk = t >> 6;            // 0..3
    const int k = combo & 3, b = (combo >> 2) & 7;
    const int part = combo >> 5;         // 0 = num, 1 = den
    float s = 0.f;
    for (int j = chunk; j < PB; j += 4)
        s += acc[(b * PB + j) * 8 + k + 4 * part];
    red[chunk][combo] = s;
    __syncthreads();
    if (t < 64) {
        float v = red[0][t] + red[1][t] + red[2][t] + red[3][t];
        const float den = __shfl(v, (t + 32) & 63, 64);
        float r = (t < 32) ? fabsf(v / den) : 0.f;
#pragma unroll
        for (int off = 32; off > 0; off >>= 1) r += __shfl_down(r, off, 64);
        if (t == 0) out[0] = (float)Kc - r * (1.0f / (float)Bb);
    }
}

extern "C" void kernel_launch(void* const* d_in, const int* in_sizes, int n_in,
                              void* d_out, int out_size, void* d_ws, size_t ws_size,
                              hipStream_t stream) {
    const float* images = (const float*)d_in[0];
    const float* labels = (const float*)d_in[1];
    float* out = (float*)d_out;
    float* acc = (float*)d_ws;  // PB*Bb blocks * 8 partials, fully overwritten each launch

    dim3 grid(GXD, GYD, Bb);    // 7 x 14 x 8
    ncut_main<<<grid, 256, 0, stream>>>(images, labels, acc);
    ncut_final<<<1, 256, 0, stream>>>(acc, out);
}